// Round 1
// baseline (1365.290 us; speedup 1.0000x reference)
//
#include <hip/hip_runtime.h>
#include <stdint.h>

#define NTOK (512 * 2048)   // 1,048,576 tokens
#define DOUT 256
#define KDIM 96
#define EPS_W 1e-8f
#define EPS_LN 1e-5f
#define NROWS 1028          // 64+256+512+128+64+4
// row starts: et 0, fc 64, sc 320, of 832, tt 960, rc 1024

// ---------------- kernel 1: scale = mean(|W|) ----------------
__global__ void k_scale(const float* __restrict__ W, float* __restrict__ scale_out) {
    __shared__ double sh[256];
    int t = threadIdx.x;
    double s = 0.0;
    for (int i = t; i < DOUT * KDIM; i += 256) s += (double)fabsf(W[i]);
    sh[t] = s;
    __syncthreads();
    for (int off = 128; off > 0; off >>= 1) {
        if (t < off) sh[t] += sh[t + off];
        __syncthreads();
    }
    if (t == 0) *scale_out = (float)(sh[0] / (double)(DOUT * KDIM));
}

// ---------------- kernel 2: build P tables (bf16) ----------------
// P[r][o] = sum_k w_q[o][coloff+k] * E_f[v][k]   (+ b[o] folded into rc rows)
__global__ void k_build(const float* __restrict__ W, const float* __restrict__ b,
                        const float* __restrict__ E0, const float* __restrict__ E1,
                        const float* __restrict__ E2, const float* __restrict__ E3,
                        const float* __restrict__ E4, const float* __restrict__ E5,
                        const float* __restrict__ scale_p,
                        unsigned short* __restrict__ P) {
    int r = blockIdx.x;
    int o = threadIdx.x;
    float scale = *scale_p;
    float d = scale + EPS_W;

    int v, coloff;
    const float* E;
    bool add_bias = false;
    if (r < 64)        { v = r;        coloff = 0;  E = E0; }
    else if (r < 320)  { v = r - 64;   coloff = 16; E = E1; }
    else if (r < 832)  { v = r - 320;  coloff = 32; E = E2; }
    else if (r < 960)  { v = r - 832;  coloff = 48; E = E3; }
    else if (r < 1024) { v = r - 960;  coloff = 64; E = E4; }
    else               { v = r - 1024; coloff = 80; E = E5; add_bias = true; }

    float acc = add_bias ? b[o] : 0.0f;
    const float* wrow = W + o * KDIM + coloff;
    const float* erow = E + v * 16;
#pragma unroll
    for (int k = 0; k < 16; k++) {
        float w = wrow[k];
        float q = rintf(w / d);                 // round-half-even, matches jnp.round
        q = fmaxf(-1.0f, fminf(1.0f, q));
        acc += (q * scale) * erow[k];
    }
    // fp32 -> bf16 round-to-nearest-even
    uint32_t u = __float_as_uint(acc);
    u += 0x7FFFu + ((u >> 16) & 1u);
    P[r * DOUT + o] = (unsigned short)(u >> 16);
}

// ---------------- kernel 3: gather-sum + LayerNorm ----------------
__device__ __forceinline__ float bf2f(unsigned short s) {
    return __uint_as_float(((uint32_t)s) << 16);
}

__global__ __launch_bounds__(256) void k_main(
    const int* __restrict__ i0, const int* __restrict__ i1, const int* __restrict__ i2,
    const int* __restrict__ i3, const int* __restrict__ i4, const int* __restrict__ i5,
    const unsigned short* __restrict__ P,
    const float* __restrict__ gamma, const float* __restrict__ beta,
    float* __restrict__ out) {
    const int lane = threadIdx.x & 63;
    const int wpb = blockDim.x >> 6;
    const int wave = blockIdx.x * wpb + (threadIdx.x >> 6);
    const int nwaves = gridDim.x * wpb;
    const int c = lane * 4;

    float4 g4 = *(const float4*)(gamma + c);
    float4 be4 = *(const float4*)(beta + c);

    for (int t = wave; t < NTOK; t += nwaves) {
        int a0 = i0[t], a1 = i1[t], a2 = i2[t], a3 = i3[t], a4 = i4[t], a5 = i5[t];
        const unsigned short* p0 = P + (a0) * DOUT + c;
        const unsigned short* p1 = P + (64 + a1) * DOUT + c;
        const unsigned short* p2 = P + (320 + a2) * DOUT + c;
        const unsigned short* p3 = P + (832 + a3) * DOUT + c;
        const unsigned short* p4 = P + (960 + a4) * DOUT + c;
        const unsigned short* p5 = P + (1024 + a5) * DOUT + c;
        ushort4 q0 = *(const ushort4*)p0;
        ushort4 q1 = *(const ushort4*)p1;
        ushort4 q2 = *(const ushort4*)p2;
        ushort4 q3 = *(const ushort4*)p3;
        ushort4 q4 = *(const ushort4*)p4;
        ushort4 q5 = *(const ushort4*)p5;

        float4 acc;
        acc.x = bf2f(q0.x) + bf2f(q1.x) + bf2f(q2.x) + bf2f(q3.x) + bf2f(q4.x) + bf2f(q5.x);
        acc.y = bf2f(q0.y) + bf2f(q1.y) + bf2f(q2.y) + bf2f(q3.y) + bf2f(q4.y) + bf2f(q5.y);
        acc.z = bf2f(q0.z) + bf2f(q1.z) + bf2f(q2.z) + bf2f(q3.z) + bf2f(q4.z) + bf2f(q5.z);
        acc.w = bf2f(q0.w) + bf2f(q1.w) + bf2f(q2.w) + bf2f(q3.w) + bf2f(q4.w) + bf2f(q5.w);

        float s = acc.x + acc.y + acc.z + acc.w;
        float ss = acc.x * acc.x + acc.y * acc.y + acc.z * acc.z + acc.w * acc.w;
#pragma unroll
        for (int off = 32; off > 0; off >>= 1) {
            s += __shfl_xor(s, off);
            ss += __shfl_xor(ss, off);
        }
        float mu = s * (1.0f / 256.0f);
        float var = ss * (1.0f / 256.0f) - mu * mu;
        float rs = rsqrtf(var + EPS_LN);

        float4 o4;
        o4.x = (acc.x - mu) * rs * g4.x + be4.x;
        o4.y = (acc.y - mu) * rs * g4.y + be4.y;
        o4.z = (acc.z - mu) * rs * g4.z + be4.z;
        o4.w = (acc.w - mu) * rs * g4.w + be4.w;
        *(float4*)(out + (size_t)t * DOUT + c) = o4;
    }
}

extern "C" void kernel_launch(void* const* d_in, const int* in_sizes, int n_in,
                              void* d_out, int out_size, void* d_ws, size_t ws_size,
                              hipStream_t stream) {
    const int* i0 = (const int*)d_in[0];
    const int* i1 = (const int*)d_in[1];
    const int* i2 = (const int*)d_in[2];
    const int* i3 = (const int*)d_in[3];
    const int* i4 = (const int*)d_in[4];
    const int* i5 = (const int*)d_in[5];
    const float* E0 = (const float*)d_in[6];
    const float* E1 = (const float*)d_in[7];
    const float* E2 = (const float*)d_in[8];
    const float* E3 = (const float*)d_in[9];
    const float* E4 = (const float*)d_in[10];
    const float* E5 = (const float*)d_in[11];
    const float* W = (const float*)d_in[12];
    const float* b = (const float*)d_in[13];
    const float* gamma = (const float*)d_in[14];
    const float* beta = (const float*)d_in[15];
    float* out = (float*)d_out;

    unsigned short* P = (unsigned short*)d_ws;
    float* scale_p = (float*)((char*)d_ws + (size_t)NROWS * DOUT * sizeof(unsigned short));

    k_scale<<<1, 256, 0, stream>>>(W, scale_p);
    k_build<<<NROWS, DOUT, 0, stream>>>(W, b, E0, E1, E2, E3, E4, E5, scale_p, P);
    k_main<<<4096, 256, 0, stream>>>(i0, i1, i2, i3, i4, i5, P, gamma, beta, out);
}